// Round 4
// baseline (753.320 us; speedup 1.0000x reference)
//
#include <hip/hip_runtime.h>
#include <math.h>

typedef __bf16 bf16x8 __attribute__((ext_vector_type(8)));
typedef float  f32x4  __attribute__((ext_vector_type(4)));

#define MFMA(a,b,c) __builtin_amdgcn_mfma_f32_16x16x32_bf16((a),(b),(c),0,0,0)

#define A_N   128
#define LDIM  256
#define FLATD 4096

// ---------------------------------------------------------------------------
// Convert the 6 latent weight arrays (each [4][256][256] fp32) to split bf16.
__global__ void k_cvt_w(const float* __restrict__ s0, const float* __restrict__ s1,
                        const float* __restrict__ s2, const float* __restrict__ s3,
                        const float* __restrict__ s4, const float* __restrict__ s5,
                        __bf16* __restrict__ dh, __bf16* __restrict__ dl) {
    const float* s;
    switch (blockIdx.y) {
        case 0: s = s0; break; case 1: s = s1; break; case 2: s = s2; break;
        case 3: s = s3; break; case 4: s = s4; break; default: s = s5; break;
    }
    size_t off  = (size_t)blockIdx.x * 2048 + threadIdx.x * 8;
    const float4* sp = (const float4*)(s + off);
    float4 x = sp[0], y = sp[1];
    float v[8] = {x.x, x.y, x.z, x.w, y.x, y.y, y.z, y.w};
    bf16x8 h, l;
    #pragma unroll
    for (int j = 0; j < 8; ++j) {
        __bf16 hh = (__bf16)v[j];
        h[j] = hh;
        l[j] = (__bf16)(v[j] - (float)hh);
    }
    size_t dst = (size_t)blockIdx.y * 262144 + off;
    *(bf16x8*)(dh + dst) = h;
    *(bf16x8*)(dl + dst) = l;
}

// ---------------------------------------------------------------------------
// Fused 4-layer latent transformer, split-bf16 projections, ILP-restructured:
// weight frags preloaded to register arrays, 3 independent MFMA acc chains.
// One block per asset; 512 threads = 8 waves = 8 heads / 32-col tiles.
__global__ __launch_bounds__(512, 2) void k_latent(
    const float* __restrict__ z,
    const __bf16* __restrict__ Wh, const __bf16* __restrict__ Wl,
    const float* __restrict__ boa,
    const float* __restrict__ g1a, const float* __restrict__ b1a,
    const float* __restrict__ fb1a, const float* __restrict__ fb2a,
    const float* __restrict__ g2a, const float* __restrict__ b2a,
    float* __restrict__ zprior, __bf16* __restrict__ Zbh, __bf16* __restrict__ Zbl)
{
    __shared__ __align__(16) char arena[57856];
    float*  zf  = (float*)arena;                    // [16][256] f32 residual
    __bf16* zbh = (__bf16*)(arena + 16384);         // [16][264]
    __bf16* zbl = (__bf16*)(arena + 24832);         // [16][264]
    __bf16* Ph  = (__bf16*)(arena + 16384);         // [8][16][32] (aliases zbh)
    __bf16* Qh  = (__bf16*)(arena + 33280);         // [8][16][32]
    __bf16* ob  = Qh;                               // [16][264]  (aliases Qh)
    __bf16* Kh  = (__bf16*)(arena + 41472);         // [8][16][32]
    __bf16* Vt  = (__bf16*)(arena + 49664);         // [8][32][16] V^T compact

    const int a    = blockIdx.x;
    const int t    = threadIdx.x;
    const int w    = t >> 6;
    const int lane = t & 63;
    const int q    = lane >> 4;
    const int r    = lane & 15;

    {   // load z -> zf, zbh/zbl; emit z_prior
        const float4* zp = (const float4*)(z + (size_t)a * 4096 + t * 8);
        float4 x = zp[0], y = zp[1];
        float4* pr = (float4*)(zprior + (size_t)a * 4096 + t * 8);
        pr[0] = x; pr[1] = y;
        float v[8] = {x.x, x.y, x.z, x.w, y.x, y.y, y.z, y.w};
        int row = t >> 5, col = (t & 31) * 8;
        float*  zr  = zf  + row * 256 + col;
        __bf16* zh  = zbh + row * 264 + col;
        __bf16* zl  = zbl + row * 264 + col;
        #pragma unroll
        for (int j = 0; j < 8; ++j) {
            zr[j] = v[j];
            __bf16 hh = (__bf16)v[j];
            zh[j] = hh;
            zl[j] = (__bf16)(v[j] - (float)hh);
        }
    }
    __syncthreads();

    auto do_ln = [&](const float* g, const float* bb) {
        int row = t >> 5, sub = t & 31;
        float* zr = zf + row * 256 + sub * 8;
        float v[8], s1 = 0.f, s2 = 0.f;
        #pragma unroll
        for (int j = 0; j < 8; ++j) { v[j] = zr[j]; s1 += v[j]; s2 += v[j]*v[j]; }
        #pragma unroll
        for (int o = 1; o <= 16; o <<= 1) {
            s1 += __shfl_xor(s1, o, 32);
            s2 += __shfl_xor(s2, o, 32);
        }
        float mean = s1 * (1.0f/256.0f);
        float var  = s2 * (1.0f/256.0f) - mean * mean;
        float inv  = rsqrtf(var + 1e-5f);
        __bf16* zh = zbh + row * 264 + sub * 8;
        __bf16* zl = zbl + row * 264 + sub * 8;
        #pragma unroll
        for (int j = 0; j < 8; ++j) {
            float y = (v[j] - mean) * inv * g[sub*8+j] + bb[sub*8+j];
            zr[j] = y;
            __bf16 hh = (__bf16)y;
            zh[j] = hh;
            zl[j] = (__bf16)(y - (float)hh);
        }
    };

    const f32x4 zero4 = {0.f, 0.f, 0.f, 0.f};
    bf16x8 zer8;
    #pragma unroll
    for (int j = 0; j < 8; ++j) zer8[j] = (__bf16)0.0f;

    // 3-term split projection: preload 16 weight frags, 3 independent chains.
    auto proj3 = [&](const __bf16* wph, const __bf16* wpl,
                     const bf16x8 (&ah)[8], const bf16x8 (&al)[8], int nc) -> f32x4 {
        bf16x8 wh_[8], wl_[8];
        #pragma unroll
        for (int ks = 0; ks < 8; ++ks) {
            size_t woff = (size_t)(nc + r)*256 + ks*32 + q*8;
            wh_[ks] = *(const bf16x8*)(wph + woff);
            wl_[ks] = *(const bf16x8*)(wpl + woff);
        }
        f32x4 c0 = zero4, c1 = zero4, c2 = zero4;
        #pragma unroll
        for (int ks = 0; ks < 8; ++ks) {
            c0 = MFMA(ah[ks], wh_[ks], c0);
            c1 = MFMA(al[ks], wh_[ks], c1);
            c2 = MFMA(ah[ks], wl_[ks], c2);
        }
        return c0 + c1 + c2;
    };
    // 2-term (single-precision A): 2 independent chains.
    auto proj2 = [&](const __bf16* wph, const __bf16* wpl,
                     const bf16x8 (&af)[8], int nc) -> f32x4 {
        bf16x8 wh_[8], wl_[8];
        #pragma unroll
        for (int ks = 0; ks < 8; ++ks) {
            size_t woff = (size_t)(nc + r)*256 + ks*32 + q*8;
            wh_[ks] = *(const bf16x8*)(wph + woff);
            wl_[ks] = *(const bf16x8*)(wpl + woff);
        }
        f32x4 c0 = zero4, c1 = zero4;
        #pragma unroll
        for (int ks = 0; ks < 8; ++ks) {
            c0 = MFMA(af[ks], wh_[ks], c0);
            c1 = MFMA(af[ks], wl_[ks], c1);
        }
        return c0 + c1;
    };

    for (int lp = 0; lp < 4; ++lp) {
        const size_t lo0 = (size_t)lp * 65536;
        const __bf16* wqh = Wh + 0*262144 + lo0; const __bf16* wql = Wl + 0*262144 + lo0;
        const __bf16* wkh = Wh + 1*262144 + lo0; const __bf16* wkl = Wl + 1*262144 + lo0;
        const __bf16* wvh = Wh + 2*262144 + lo0; const __bf16* wvl = Wl + 2*262144 + lo0;
        const __bf16* woh = Wh + 3*262144 + lo0; const __bf16* wol = Wl + 3*262144 + lo0;
        const __bf16* f1h = Wh + 4*262144 + lo0; const __bf16* f1l = Wl + 4*262144 + lo0;
        const __bf16* f2h = Wh + 5*262144 + lo0; const __bf16* f2l = Wl + 5*262144 + lo0;
        const float* bo  = boa  + lp*256;
        const float* g1  = g1a  + lp*256; const float* b1 = b1a + lp*256;
        const float* fb1 = fb1a + lp*256; const float* fb2 = fb2a + lp*256;
        const float* g2  = g2a  + lp*256; const float* b2 = b2a + lp*256;

        // ---- q,k,v projections ----
        {
            bf16x8 afh[8], afl[8];
            #pragma unroll
            for (int ks = 0; ks < 8; ++ks) {
                afh[ks] = *(const bf16x8*)(zbh + r*264 + ks*32 + q*8);
                afl[ks] = *(const bf16x8*)(zbl + r*264 + ks*32 + q*8);
            }
            #pragma unroll
            for (int which = 0; which < 3; ++which) {
                const __bf16* wph = (which == 0) ? wqh : ((which == 1) ? wkh : wvh);
                const __bf16* wpl = (which == 0) ? wql : ((which == 1) ? wkl : wvl);
                #pragma unroll
                for (int nt = 0; nt < 2; ++nt) {
                    f32x4 acc = proj3(wph, wpl, afh, afl, w*32 + nt*16);
                    #pragma unroll
                    for (int i = 0; i < 4; ++i) {
                        int mrow = q*4 + i;
                        if (which == 0)      Qh[(w*16 + mrow)*32 + nt*16 + r] = (__bf16)acc[i];
                        else if (which == 1) Kh[(w*16 + mrow)*32 + nt*16 + r] = (__bf16)acc[i];
                        else                 Vt[(w*32 + nt*16 + r)*16 + mrow] = (__bf16)acc[i];
                    }
                }
            }
        }
        __syncthreads();   // Qh/Kh/Vt visible; zb reads done (Ph may alias)

        // ---- scores + softmax, head w per wave ----
        {
            bf16x8 qa = *(const bf16x8*)(Qh + (w*16 + r)*32 + q*8);
            bf16x8 ka = *(const bf16x8*)(Kh + (w*16 + r)*32 + q*8);
            f32x4 s = MFMA(qa, ka, zero4);   // S[i=q*4+reg][j=r], K = hd = 32
            #pragma unroll
            for (int i = 0; i < 4; ++i) {
                float sc = s[i] * 0.17677669529663687f;
                float mx = sc;
                #pragma unroll
                for (int o = 1; o <= 8; o <<= 1) mx = fmaxf(mx, __shfl_xor(mx, o, 16));
                float e = __expf(sc - mx);
                float sm = e;
                #pragma unroll
                for (int o = 1; o <= 8; o <<= 1) sm += __shfl_xor(sm, o, 16);
                Ph[(w*16 + q*4 + i)*32 + r]      = (__bf16)(e / sm);
                Ph[(w*16 + q*4 + i)*32 + 16 + r] = (__bf16)0.0f;   // k-pad
            }
        }
        __syncthreads();   // all Qh/Kh reads done (ob may alias)

        // ---- O = P @ V (B rows k>=16 forced zero in registers) ----
        {
            bf16x8 pa = *(const bf16x8*)(Ph + (w*16 + r)*32 + q*8);
            #pragma unroll
            for (int nt = 0; nt < 2; ++nt) {
                bf16x8 vb = (q < 2)
                    ? *(const bf16x8*)(Vt + (w*32 + nt*16 + r)*16 + q*8) : zer8;
                f32x4 o = MFMA(pa, vb, zero4);
                #pragma unroll
                for (int i = 0; i < 4; ++i)
                    ob[(q*4 + i)*264 + w*32 + nt*16 + r] = (__bf16)o[i];
            }
        }
        __syncthreads();

        // ---- wo projection + bias + residual ----
        {
            bf16x8 af[8];
            #pragma unroll
            for (int ks = 0; ks < 8; ++ks)
                af[ks] = *(const bf16x8*)(ob + r*264 + ks*32 + q*8);
            #pragma unroll
            for (int nt = 0; nt < 2; ++nt) {
                int nc = w*32 + nt*16;
                f32x4 acc = proj2(woh, wol, af, nc);
                #pragma unroll
                for (int i = 0; i < 4; ++i) {
                    int row = q*4 + i, col = nc + r;
                    zf[row*256 + col] = acc[i] + bo[col] + zf[row*256 + col];
                }
            }
        }
        __syncthreads();
        do_ln(g1, b1);
        __syncthreads();

        // ---- FF1: relu(z @ f1^T + fb1) -> ob ----
        {
            bf16x8 afh[8], afl[8];
            #pragma unroll
            for (int ks = 0; ks < 8; ++ks) {
                afh[ks] = *(const bf16x8*)(zbh + r*264 + ks*32 + q*8);
                afl[ks] = *(const bf16x8*)(zbl + r*264 + ks*32 + q*8);
            }
            #pragma unroll
            for (int nt = 0; nt < 2; ++nt) {
                int nc = w*32 + nt*16;
                f32x4 acc = proj3(f1h, f1l, afh, afl, nc);
                #pragma unroll
                for (int i = 0; i < 4; ++i) {
                    int row = q*4 + i, col = nc + r;
                    ob[row*264 + col] = (__bf16)fmaxf(acc[i] + fb1[col], 0.0f);
                }
            }
        }
        __syncthreads();

        // ---- FF2 + bias + residual ----
        {
            bf16x8 af[8];
            #pragma unroll
            for (int ks = 0; ks < 8; ++ks)
                af[ks] = *(const bf16x8*)(ob + r*264 + ks*32 + q*8);
            #pragma unroll
            for (int nt = 0; nt < 2; ++nt) {
                int nc = w*32 + nt*16;
                f32x4 acc = proj2(f2h, f2l, af, nc);
                #pragma unroll
                for (int i = 0; i < 4; ++i) {
                    int row = q*4 + i, col = nc + r;
                    zf[row*256 + col] = acc[i] + fb2[col] + zf[row*256 + col];
                }
            }
        }
        __syncthreads();
        do_ln(g2, b2);
        __syncthreads();
    }

    {   // emit final z split as bf16 [A_N][4096]
        int row = t >> 5, col = (t & 31) * 8;
        *(bf16x8*)(Zbh + (size_t)a * 4096 + row * 256 + col) =
            *(const bf16x8*)(zbh + row * 264 + col);
        *(bf16x8*)(Zbl + (size_t)a * 4096 + row * 256 + col) =
            *(const bf16x8*)(zbl + row * 264 + col);
    }
}

// ---------------------------------------------------------------------------
// CANN q/k/v GEMM, split-bf16. A (Z) direct global->register fragments (L2-
// resident, no LDS round-trip); B (W fp32) staged to LDS with inline hi/lo
// conversion. Epilogue: Q/K -> split bf16 row-major; V -> split bf16 TRANSPOSED
// [4096][128] for the PV MFMA. grid (128, 3) x 256 (4 waves, m-tile 32/wave).
__global__ __launch_bounds__(256) void k_cann_gemm(
    const __bf16* __restrict__ Zh, const __bf16* __restrict__ Zl,
    const float* __restrict__ W0, const float* __restrict__ W1, const float* __restrict__ W2,
    const float* __restrict__ b0, const float* __restrict__ b1, const float* __restrict__ b2,
    __bf16* __restrict__ Qh, __bf16* __restrict__ Ql,
    __bf16* __restrict__ Kh, __bf16* __restrict__ Kl,
    __bf16* __restrict__ VtH, __bf16* __restrict__ VtL)
{
    const float* W; const float* bias;
    if (blockIdx.y == 0)      { W = W0; bias = b0; }
    else if (blockIdx.y == 1) { W = W1; bias = b1; }
    else                      { W = W2; bias = b2; }

    __shared__ __bf16 Bsh[32 * 72];
    __shared__ __bf16 Bsl[32 * 72];

    const int t = threadIdx.x;
    const int w = t >> 6, lane = t & 63, q = lane >> 4, r = lane & 15;
    const int n0 = blockIdx.x * 32;
    const int m0 = w * 32;
    const int br = t >> 3, bc = t & 7;

    const f32x4 zero4 = {0.f, 0.f, 0.f, 0.f};
    f32x4 acc[2][2] = {{zero4, zero4}, {zero4, zero4}};

    for (int k0 = 0; k0 < FLATD; k0 += 64) {
        // A fragments: direct global->register (8 x 16B, independent)
        bf16x8 ah[2][2], al[2][2];
        #pragma unroll
        for (int ms = 0; ms < 2; ++ms)
            #pragma unroll
            for (int ks = 0; ks < 2; ++ks) {
                size_t zoff = (size_t)(m0 + ms*16 + r) * FLATD + k0 + ks*32 + q*8;
                ah[ms][ks] = *(const bf16x8*)(Zh + zoff);
                al[ms][ks] = *(const bf16x8*)(Zl + zoff);
            }
        // B stage: fp32 -> hi/lo bf16 into LDS
        {
            const float4* wp = (const float4*)(W + (size_t)(n0 + br) * FLATD + k0 + bc*8);
            float4 x = wp[0], y = wp[1];
            float v[8] = {x.x, x.y, x.z, x.w, y.x, y.y, y.z, y.w};
            bf16x8 h, l;
            #pragma unroll
            for (int j = 0; j < 8; ++j) {
                __bf16 hh = (__bf16)v[j];
                h[j] = hh;
                l[j] = (__bf16)(v[j] - (float)hh);
            }
            *(bf16x8*)(Bsh + br*72 + bc*8) = h;
            *(bf16x8*)(Bsl + br*72 + bc*8) = l;
        }
        __syncthreads();
        #pragma unroll
        for (int ks = 0; ks < 2; ++ks) {
            bf16x8 g0h = *(const bf16x8*)(Bsh + r*72        + ks*32 + q*8);
            bf16x8 g1h = *(const bf16x8*)(Bsh + (16 + r)*72 + ks*32 + q*8);
            bf16x8 g0l = *(const bf16x8*)(Bsl + r*72        + ks*32 + q*8);
            bf16x8 g1l = *(const bf16x8*)(Bsl + (16 + r)*72 + ks*32 + q*8);
            acc[0][0] = MFMA(ah[0][ks], g0h, acc[0][0]);
            acc[0][0] = MFMA(al[0][ks], g0h, acc[0][0]);
            acc[0][0] = MFMA(ah[0][ks], g0l, acc[0][0]);
            acc[0][1] = MFMA(ah[0][ks], g1h, acc[0][1]);
            acc[0][1] = MFMA(al[0][ks], g1h, acc[0][1]);
            acc[0][1] = MFMA(ah[0][ks], g1l, acc[0][1]);
            acc[1][0] = MFMA(ah[1][ks], g0h, acc[1][0]);
            acc[1][0] = MFMA(al[1][ks], g0h, acc[1][0]);
            acc[1][0] = MFMA(ah[1][ks], g0l, acc[1][0]);
            acc[1][1] = MFMA(ah[1][ks], g1h, acc[1][1]);
            acc[1][1] = MFMA(al[1][ks], g1h, acc[1][1]);
            acc[1][1] = MFMA(ah[1][ks], g1l, acc[1][1]);
        }
        __syncthreads();
    }

    const int y = blockIdx.y;
    #pragma unroll
    for (int mi = 0; mi < 2; ++mi)
        #pragma unroll
        for (int ni = 0; ni < 2; ++ni)
            #pragma unroll
            for (int i = 0; i < 4; ++i) {
                int row = m0 + mi*16 + q*4 + i;
                int col = n0 + ni*16 + r;
                float val = acc[mi][ni][i] + bias[col];
                __bf16 hh = (__bf16)val;
                __bf16 ll = (__bf16)(val - (float)hh);
                if (y == 0)      { Qh[(size_t)row*FLATD + col] = hh; Ql[(size_t)row*FLATD + col] = ll; }
                else if (y == 1) { Kh[(size_t)row*FLATD + col] = hh; Kl[(size_t)row*FLATD + col] = ll; }
                else             { VtH[(size_t)col*A_N + row] = hh; VtL[(size_t)col*A_N + row] = ll; }
            }
}

// ---------------------------------------------------------------------------
// CANN scores + softmax via MFMA: S = Q@K^T/16, P = softmax rows -> split bf16.
// grid 4 blocks x 256 (4 waves); block = 32 rows x full 128 cols; K=4096.
// No LDS / barriers in the K-loop.
__global__ __launch_bounds__(256) void k_cann_scores(
    const __bf16* __restrict__ Qh, const __bf16* __restrict__ Ql,
    const __bf16* __restrict__ Kh, const __bf16* __restrict__ Kl,
    __bf16* __restrict__ Pbh, __bf16* __restrict__ Pbl)
{
    __shared__ float S[32 * 132];
    const int t = threadIdx.x;
    const int w = t >> 6, lane = t & 63, q = lane >> 4, r = lane & 15;
    const int i0 = blockIdx.x * 32;

    const f32x4 zero4 = {0.f, 0.f, 0.f, 0.f};
    f32x4 acc[2][2] = {{zero4, zero4}, {zero4, zero4}};

    for (int k0 = 0; k0 < FLATD; k0 += 32) {
        bf16x8 qah[2], qal[2], kbh[2], kbl[2];
        #pragma unroll
        for (int ms = 0; ms < 2; ++ms) {
            size_t qoff = (size_t)(i0 + ms*16 + r) * FLATD + k0 + q*8;
            qah[ms] = *(const bf16x8*)(Qh + qoff);
            qal[ms] = *(const bf16x8*)(Ql + qoff);
        }
        #pragma unroll
        for (int ns = 0; ns < 2; ++ns) {
            size_t koff = (size_t)(w*32 + ns*16 + r) * FLATD + k0 + q*8;
            kbh[ns] = *(const bf16x8*)(Kh + koff);
            kbl[ns] = *(const bf16x8*)(Kl + koff);
        }
        #pragma unroll
        for (int ms = 0; ms < 2; ++ms)
            #pragma unroll
            for (int ns = 0; ns < 2; ++ns) {
                acc[ms][ns] = MFMA(qah[ms], kbh[ns], acc[ms][ns]);
                acc[ms][ns] = MFMA(qal[ms], kbh[ns], acc[ms][ns]);
                acc[ms][ns] = MFMA(qah[ms], kbl[ns], acc[ms][ns]);
            }
    }
    #pragma unroll
    for (int ms = 0; ms < 2; ++ms)
        #pragma unroll
        for (int ns = 0; ns < 2; ++ns)
            #pragma unroll
            for (int i = 0; i < 4; ++i)
                S[(ms*16 + q*4 + i)*132 + w*32 + ns*16 + r] = acc[ms][ns][i] * 0.0625f;
    __syncthreads();

    // softmax: 8 threads per row, 16 cols each
    {
        int row = t >> 3, cb = (t & 7) * 16;
        float e[16];
        float mx = -1e30f;
        #pragma unroll
        for (int c = 0; c < 16; ++c) { e[c] = S[row*132 + cb + c]; mx = fmaxf(mx, e[c]); }
        #pragma unroll
        for (int o = 1; o <= 4; o <<= 1) mx = fmaxf(mx, __shfl_xor(mx, o, 8));
        float sm = 0.f;
        #pragma unroll
        for (int c = 0; c < 16; ++c) { e[c] = __expf(e[c] - mx); sm += e[c]; }
        #pragma unroll
        for (int o = 1; o <= 4; o <<= 1) sm += __shfl_xor(sm, o, 8);
        float inv = 1.0f / sm;
        #pragma unroll
        for (int c = 0; c < 16; ++c) {
            float p = e[c] * inv;
            __bf16 hh = (__bf16)p;
            Pbh[(size_t)(i0 + row)*A_N + cb + c] = hh;
            Pbl[(size_t)(i0 + row)*A_N + cb + c] = (__bf16)(p - (float)hh);
        }
    }
}

// ---------------------------------------------------------------------------
// H = P @ V via MFMA using transposed split-bf16 V. M=128, N=4096, K=128.
// grid 64 blocks x 256 (4 waves); wave: 16 cols x all 128 rows.
__global__ __launch_bounds__(256) void k_cann_pv(
    const __bf16* __restrict__ Pbh, const __bf16* __restrict__ Pbl,
    const __bf16* __restrict__ VtH, const __bf16* __restrict__ VtL,
    float* __restrict__ H)
{
    const int t = threadIdx.x;
    const int w = t >> 6, lane = t & 63, q = lane >> 4, r = lane & 15;
    const int n0 = blockIdx.x * 64;
    const int nc = n0 + w*16;

    const f32x4 zero4 = {0.f, 0.f, 0.f, 0.f};
    f32x4 acc[8] = {zero4, zero4, zero4, zero4, zero4, zero4, zero4, zero4};

    #pragma unroll
    for (int ks = 0; ks < 4; ++ks) {
        size_t voff = (size_t)(nc + r) * A_N + ks*32 + q*8;
        bf16x8 vh = *(const bf16x8*)(VtH + voff);
        bf16x8 vl = *(const bf16x8*)(VtL + voff);
        #pragma unroll
        for (int ms = 0; ms < 8; ++ms) {
            size_t poff = (size_t)(ms*16 + r) * A_N + ks*32 + q*8;
            bf16x8 ph = *(const bf16x8*)(Pbh + poff);
            bf16x8 pl = *(const bf16x8*)(Pbl + poff);
            acc[ms] = MFMA(ph, vh, acc[ms]);
            acc[ms] = MFMA(pl, vh, acc[ms]);
            acc[ms] = MFMA(ph, vl, acc[ms]);
        }
    }
    #pragma unroll
    for (int ms = 0; ms < 8; ++ms)
        #pragma unroll
        for (int i = 0; i < 4; ++i)
            H[(size_t)(ms*16 + q*4 + i) * FLATD + nc + r] = acc[ms][i];
}

// ---------------------------------------------------------------------------
extern "C" void kernel_launch(void* const* d_in, const int* in_sizes, int n_in,
                              void* d_out, int out_size, void* d_ws, size_t ws_size,
                              hipStream_t stream) {
    (void)in_sizes; (void)n_in; (void)out_size; (void)ws_size;

    const float* z      = (const float*)d_in[1];
    const float* s_wq   = (const float*)d_in[15];
    const float* s_wk   = (const float*)d_in[16];
    const float* s_wv   = (const float*)d_in[17];
    const float* s_wo   = (const float*)d_in[18];
    const float* s_bo   = (const float*)d_in[19];
    const float* s_ln1g = (const float*)d_in[20];
    const float* s_ln1b = (const float*)d_in[21];
    const float* s_fw1  = (const float*)d_in[22];
    const float* s_fb1  = (const float*)d_in[23];
    const float* s_fw2  = (const float*)d_in[24];
    const float* s_fb2  = (const float*)d_in[25];
    const float* s_ln2g = (const float*)d_in[26];
    const float* s_ln2b = (const float*)d_in[27];
    const float* q_w    = (const float*)d_in[28];
    const float* q_b    = (const float*)d_in[29];
    const float* k_w    = (const float*)d_in[30];
    const float* k_b    = (const float*)d_in[31];
    const float* v_w    = (const float*)d_in[32];
    const float* v_b    = (const float*)d_in[33];

    float* out    = (float*)d_out;
    float* Hout   = out;
    float* Zprior = out + 524288;

    // Workspace map (8.1 MB):
    //  [0,6MB): Wh+Wl during latent; then reused as Qh/Ql/Kh/Kl/VtH/VtL
    char* w8 = (char*)d_ws;
    __bf16* Wh  = (__bf16*)w8;                     // 3 MB
    __bf16* Wl  = (__bf16*)(w8 + 3145728);         // 3 MB
    __bf16* Qh  = (__bf16*)w8;                     // 1 MB each
    __bf16* Ql  = (__bf16*)(w8 + 1048576);
    __bf16* Kh  = (__bf16*)(w8 + 2097152);
    __bf16* Kl  = (__bf16*)(w8 + 3145728);
    __bf16* VtH = (__bf16*)(w8 + 4194304);
    __bf16* VtL = (__bf16*)(w8 + 5242880);
    __bf16* Zbh = (__bf16*)(w8 + 6291456);         // 1 MB
    __bf16* Zbl = (__bf16*)(w8 + 7340032);         // 1 MB
    __bf16* Pbh = (__bf16*)(w8 + 8388608);         // 32 KB
    __bf16* Pbl = (__bf16*)(w8 + 8421376);         // 32 KB

    k_cvt_w<<<dim3(128, 6), 256, 0, stream>>>(s_wq, s_wk, s_wv, s_wo, s_fw1, s_fw2,
                                              Wh, Wl);

    k_latent<<<A_N, 512, 0, stream>>>(z, Wh, Wl, s_bo, s_ln1g, s_ln1b,
                                      s_fb1, s_fb2, s_ln2g, s_ln2b,
                                      Zprior, Zbh, Zbl);

    k_cann_gemm<<<dim3(FLATD / 32, 3), 256, 0, stream>>>(Zbh, Zbl, q_w, k_w, v_w,
                                                         q_b, k_b, v_b,
                                                         Qh, Ql, Kh, Kl, VtH, VtL);

    k_cann_scores<<<4, 256, 0, stream>>>(Qh, Ql, Kh, Kl, Pbh, Pbl);
    k_cann_pv<<<dim3(FLATD / 64), 256, 0, stream>>>(Pbh, Pbl, VtH, VtL, Hout);
}